// Round 6
// baseline (348.241 us; speedup 1.0000x reference)
//
#include <hip/hip_runtime.h>

#define F_IN 256
#define HID  16
#define NCLS 40
#define NB   512      // nodes per bucket (dest >> 9)
#define SPAN 4096     // edges per bscatter block

static inline int cdiv(int a, int b) { return (a + b - 1) / b; }

typedef short bf16x8 __attribute__((ext_vector_type(8)));
typedef float f32x4  __attribute__((ext_vector_type(4)));

// ---------- bf16 helpers (top 16 bits of fp32, RNE) ----------
__device__ __forceinline__ float bf_lo(unsigned int u) { return __uint_as_float(u << 16); }
__device__ __forceinline__ float bf_hi(unsigned int u) { return __uint_as_float(u & 0xFFFF0000u); }
__device__ __forceinline__ unsigned short f2bf(float a) {
    unsigned int u = __float_as_uint(a);
    return (unsigned short)((u + 0x7FFFu + ((u >> 16) & 1u)) >> 16);
}
__device__ __forceinline__ unsigned int pack_bf(float a, float b) {
    return (unsigned int)f2bf(a) | ((unsigned int)f2bf(b) << 16);
}

// ---------- per-bucket edge counts (LDS hist -> few global atomics) ----------
__global__ void __launch_bounds__(256) bcount_kernel(const int* __restrict__ col,
                                                     int* __restrict__ bkt_cnt, int E, int K) {
    __shared__ int h[256];
    int t = threadIdx.x;
    h[t] = 0;
    __syncthreads();
    int E4 = E >> 2;
    const int4* c4 = (const int4*)col;
    for (int e = blockIdx.x * 256 + t; e < E4; e += gridDim.x * 256) {
        int4 v = c4[e];
        atomicAdd(&h[v.x >> 9], 1);
        atomicAdd(&h[v.y >> 9], 1);
        atomicAdd(&h[v.z >> 9], 1);
        atomicAdd(&h[v.w >> 9], 1);
    }
    for (int e = (E4 << 2) + blockIdx.x * 256 + t; e < E; e += gridDim.x * 256)
        atomicAdd(&h[col[e] >> 9], 1);
    __syncthreads();
    if (t < K && h[t]) atomicAdd(&bkt_cnt[t], h[t]);
}

// ---------- exclusive scan of bucket counts (K <= 256), init cursors ----------
__global__ void __launch_bounds__(256) bscan_kernel(const int* __restrict__ bkt_cnt,
                                                    int* __restrict__ bkt_off,
                                                    int* __restrict__ bkt_cur, int K) {
    __shared__ int s[256];
    int t = threadIdx.x;
    int v = (t < K) ? bkt_cnt[t] : 0;
    s[t] = v;
    __syncthreads();
    for (int off = 1; off < 256; off <<= 1) {
        int x = (t >= off) ? s[t - off] : 0;
        __syncthreads();
        s[t] += x;
        __syncthreads();
    }
    int excl = s[t] - v;
    if (t < K) { bkt_off[t] = excl; bkt_cur[t] = excl; }
    if (t == K - 1) bkt_off[K] = excl + v;
}

// ---------- bucketed scatter: runs of packed entries per (block,bucket) ----------
// entry = row | (local_dest << 17); row < 2^17, local_dest < 512
// Phase-3 loop 8x-unrolled: 8 independent load->LDS-atomic->store chains per
// iteration so their latency windows overlap (SPAN/256 = 16/thread = 2 groups).
__global__ void __launch_bounds__(256) bscatter_kernel(const int* __restrict__ row,
                                                       const int* __restrict__ col,
                                                       int* __restrict__ bkt_cur,
                                                       int* __restrict__ entries, int E) {
    __shared__ int cnt[256];
    __shared__ int base[256];
    int t = threadIdx.x;
    int start = blockIdx.x * SPAN;
    int end = min(start + SPAN, E);
    cnt[t] = 0;
    __syncthreads();
    int m = end - start;
    int m4 = m >> 2;
    const int4* c4 = (const int4*)(col + start);
    for (int i = t; i < m4; i += 256) {
        int4 v = c4[i];
        atomicAdd(&cnt[v.x >> 9], 1);
        atomicAdd(&cnt[v.y >> 9], 1);
        atomicAdd(&cnt[v.z >> 9], 1);
        atomicAdd(&cnt[v.w >> 9], 1);
    }
    for (int i = (m4 << 2) + t; i < m; i += 256)
        atomicAdd(&cnt[col[start + i] >> 9], 1);
    __syncthreads();
    int c = cnt[t];
    base[t] = c ? atomicAdd(&bkt_cur[t], c) : 0;
    cnt[t] = 0;
    __syncthreads();
    int e = start + t;
    for (; e + 1792 < end; e += 2048) {
        int c0 = col[e];
        int c1 = col[e + 256];
        int c2 = col[e + 512];
        int c3 = col[e + 768];
        int c4v = col[e + 1024];
        int c5 = col[e + 1280];
        int c6 = col[e + 1536];
        int c7 = col[e + 1792];
        int r0 = row[e];
        int r1 = row[e + 256];
        int r2 = row[e + 512];
        int r3 = row[e + 768];
        int r4 = row[e + 1024];
        int r5 = row[e + 1280];
        int r6 = row[e + 1536];
        int r7 = row[e + 1792];
        int b0 = c0 >> 9, b1 = c1 >> 9, b2 = c2 >> 9, b3 = c3 >> 9;
        int b4 = c4v >> 9, b5 = c5 >> 9, b6 = c6 >> 9, b7 = c7 >> 9;
        int p0 = base[b0] + atomicAdd(&cnt[b0], 1);
        int p1 = base[b1] + atomicAdd(&cnt[b1], 1);
        int p2 = base[b2] + atomicAdd(&cnt[b2], 1);
        int p3 = base[b3] + atomicAdd(&cnt[b3], 1);
        int p4 = base[b4] + atomicAdd(&cnt[b4], 1);
        int p5 = base[b5] + atomicAdd(&cnt[b5], 1);
        int p6 = base[b6] + atomicAdd(&cnt[b6], 1);
        int p7 = base[b7] + atomicAdd(&cnt[b7], 1);
        entries[p0] = r0 | ((c0 & (NB - 1)) << 17);
        entries[p1] = r1 | ((c1 & (NB - 1)) << 17);
        entries[p2] = r2 | ((c2 & (NB - 1)) << 17);
        entries[p3] = r3 | ((c3 & (NB - 1)) << 17);
        entries[p4] = r4 | ((c4v & (NB - 1)) << 17);
        entries[p5] = r5 | ((c5 & (NB - 1)) << 17);
        entries[p6] = r6 | ((c6 & (NB - 1)) << 17);
        entries[p7] = r7 | ((c7 & (NB - 1)) << 17);
    }
    for (; e < end; e += 256) {
        int cc = col[e];
        int bkt = cc >> 9;
        int pos = base[bkt] + atomicAdd(&cnt[bkt], 1);
        entries[pos] = row[e] | ((cc & (NB - 1)) << 17);
    }
}

// ---------- per-bucket CSR finalize: deg/dinv, shuffle scan, DIRECT global scatter ----
// 1024 threads (halves per-thread atomic-chain length vs 512); no lsrc LDS staging —
// scattered csr_src writes stay within a ~64KB bucket window handled by one CU's L2.
__global__ void __launch_bounds__(1024) bfill_kernel(const int* __restrict__ entries,
                                                     const int* __restrict__ bkt_off,
                                                     int* __restrict__ csr_src,
                                                     int* __restrict__ csr_off,
                                                     float* __restrict__ dinv, int n, int E) {
    __shared__ int sdeg[NB];
    __shared__ int soff[NB];
    __shared__ int wtot[8];
    int t = threadIdx.x;
    int wv = t >> 6, ln = t & 63;
    int b = blockIdx.x;
    int node0 = b << 9;
    int nn = min(NB, n - node0);
    int seg0 = bkt_off[b], seg1 = bkt_off[b + 1];
    int m = seg1 - seg0;
    if (t < NB) sdeg[t] = 0;
    __syncthreads();
    {   // histogram, 4-deep unrolled over 1024 threads
        int i = t;
        for (; i + 3072 < m; i += 4096) {
            int u0 = entries[seg0 + i];
            int u1 = entries[seg0 + i + 1024];
            int u2 = entries[seg0 + i + 2048];
            int u3 = entries[seg0 + i + 3072];
            atomicAdd(&sdeg[u0 >> 17], 1);
            atomicAdd(&sdeg[u1 >> 17], 1);
            atomicAdd(&sdeg[u2 >> 17], 1);
            atomicAdd(&sdeg[u3 >> 17], 1);
        }
        for (; i < m; i += 1024) atomicAdd(&sdeg[entries[seg0 + i] >> 17], 1);
    }
    __syncthreads();
    int v = 0, inc = 0;
    if (t < NB) {
        v = sdeg[t];
        inc = v;
#pragma unroll
        for (int o = 1; o < 64; o <<= 1) {
            int u = __shfl_up(inc, o);
            if (ln >= o) inc += u;
        }
        if (ln == 63) wtot[wv] = inc;
    }
    __syncthreads();
    if (wv == 0) {
        int tv = (ln < 8) ? wtot[ln] : 0;
        int ti = tv;
#pragma unroll
        for (int o = 1; o < 8; o <<= 1) {
            int u = __shfl_up(ti, o);
            if (ln >= o) ti += u;
        }
        if (ln < 8) wtot[ln] = ti - tv;  // exclusive wave base
    }
    __syncthreads();
    if (t < NB) {
        int excl = inc - v + wtot[wv];
        soff[t] = excl;
        sdeg[t] = 0;     // reuse as cursor
        if (t < nn) {
            csr_off[node0 + t] = seg0 + excl;
            dinv[node0 + t] = rsqrtf((float)(v + 1));  // +1 self-loop
        }
    }
    if (b == gridDim.x - 1 && t == 0) csr_off[n] = E;
    __syncthreads();
    {   // scatter directly to global csr_src, 4-deep unrolled
        int i = t;
        for (; i + 3072 < m; i += 4096) {
            int u0 = entries[seg0 + i];
            int u1 = entries[seg0 + i + 1024];
            int u2 = entries[seg0 + i + 2048];
            int u3 = entries[seg0 + i + 3072];
            int l0 = u0 >> 17, l1 = u1 >> 17, l2 = u2 >> 17, l3 = u3 >> 17;
            int p0 = soff[l0] + atomicAdd(&sdeg[l0], 1);
            int p1 = soff[l1] + atomicAdd(&sdeg[l1], 1);
            int p2 = soff[l2] + atomicAdd(&sdeg[l2], 1);
            int p3 = soff[l3] + atomicAdd(&sdeg[l3], 1);
            csr_src[seg0 + p0] = u0 & 0x1FFFF;
            csr_src[seg0 + p1] = u1 & 0x1FFFF;
            csr_src[seg0 + p2] = u2 & 0x1FFFF;
            csr_src[seg0 + p3] = u3 & 0x1FFFF;
        }
        for (; i < m; i += 1024) {
            int u = entries[seg0 + i];
            int l = u >> 17;
            int pos = soff[l] + atomicAdd(&sdeg[l], 1);
            csr_src[seg0 + pos] = u & 0x1FFFF;
        }
    }
}

// ---------- f1 = bf16( dinv[r] * (x @ W1)[r] ) via MFMA ----------
__global__ void __launch_bounds__(256) xw_kernel(const float* __restrict__ x,
                                                 const float* __restrict__ W1,
                                                 const float* __restrict__ dinv,
                                                 unsigned short* __restrict__ f1,
                                                 int ntiles) {
    int lane = threadIdx.x & 63;
    int m = lane & 15;   // A row / B col / D col
    int q = lane >> 4;   // k-quad
    bf16x8 bfrag[8];
#pragma unroll
    for (int c = 0; c < 8; ++c) {
        const float* wp = W1 + (size_t)(c * 32 + q * 8) * HID + m;
#pragma unroll
        for (int j = 0; j < 8; ++j) bfrag[c][j] = (short)f2bf(wp[(size_t)j * HID]);
    }
    int wid = (blockIdx.x * 256 + threadIdx.x) >> 6;
    if (wid >= ntiles) return;
    int r0 = wid << 4;
    const float* xrow = x + (size_t)(r0 + m) * F_IN + q * 8;
    f32x4 acc = {0.f, 0.f, 0.f, 0.f};
#pragma unroll
    for (int c = 0; c < 8; ++c) {
        float4 v0 = *(const float4*)(xrow + c * 32);
        float4 v1 = *(const float4*)(xrow + c * 32 + 4);
        bf16x8 afrag;
        afrag[0] = (short)f2bf(v0.x);
        afrag[1] = (short)f2bf(v0.y);
        afrag[2] = (short)f2bf(v0.z);
        afrag[3] = (short)f2bf(v0.w);
        afrag[4] = (short)f2bf(v1.x);
        afrag[5] = (short)f2bf(v1.y);
        afrag[6] = (short)f2bf(v1.z);
        afrag[7] = (short)f2bf(v1.w);
        acc = __builtin_amdgcn_mfma_f32_16x16x32_bf16(afrag, bfrag[c], acc, 0, 0, 0);
    }
#pragma unroll
    for (int i = 0; i < 4; ++i) {
        int r = r0 + q * 4 + i;
        f1[(size_t)r * HID + m] = f2bf(dinv[r] * acc[i]);
    }
}

// ---------- layer-1 aggregation: 2 nodes/wave, 8 slots x 4 j (uint2 gathers),
// predicated full-width batches, self-loop load hoisted above the loop ----------
__global__ void __launch_bounds__(256) agg1_kernel(const uint2* __restrict__ feat2,
                                                   const float* __restrict__ dinv,
                                                   const int* __restrict__ csr_off,
                                                   const int* __restrict__ csr_src,
                                                   const float* __restrict__ b1,
                                                   uint2* __restrict__ f2, int n) {
    int wid = (blockIdx.x * 256 + threadIdx.x) >> 6;
    int w0 = wid << 1;
    if (w0 >= n) return;
    int lane = threadIdx.x & 63;
    int j = lane & 3;                 // feature quad: feats 4j..4j+3
    int s = (lane >> 2) & 7;          // slot 0..7
    int node = w0 + (lane >> 5);      // A for lanes<32, B for lanes>=32
    bool act = node < n;
    int start = 0, end = 0;
    if (act) { start = csr_off[node]; end = csr_off[node + 1]; }
    // self-loop load issued unconditionally (clamped addr) so it overlaps the loop
    bool sl = act && (s == 0);
    uint2 us = feat2[(size_t)(act ? node : 0) * 4 + j];
    float a0 = 0.f, a1 = 0.f, a2 = 0.f, a3 = 0.f;
    for (int base = start + s; base < end; base += 32) {
        int e1 = base + 8, e2 = base + 16, e3 = base + 24;
        bool v1 = e1 < end, v2 = e2 < end, v3 = e3 < end;
        int i0 = csr_src[base];
        int i1 = csr_src[v1 ? e1 : base];
        int i2 = csr_src[v2 ? e2 : base];
        int i3 = csr_src[v3 ? e3 : base];
        uint2 u0 = feat2[(size_t)i0 * 4 + j];
        uint2 u1 = feat2[(size_t)i1 * 4 + j];
        uint2 u2 = feat2[(size_t)i2 * 4 + j];
        uint2 u3 = feat2[(size_t)i3 * 4 + j];
        if (!v1) { u1.x = 0u; u1.y = 0u; }
        if (!v2) { u2.x = 0u; u2.y = 0u; }
        if (!v3) { u3.x = 0u; u3.y = 0u; }
        a0 += bf_lo(u0.x); a1 += bf_hi(u0.x); a2 += bf_lo(u0.y); a3 += bf_hi(u0.y);
        a0 += bf_lo(u1.x); a1 += bf_hi(u1.x); a2 += bf_lo(u1.y); a3 += bf_hi(u1.y);
        a0 += bf_lo(u2.x); a1 += bf_hi(u2.x); a2 += bf_lo(u2.y); a3 += bf_hi(u2.y);
        a0 += bf_lo(u3.x); a1 += bf_hi(u3.x); a2 += bf_lo(u3.y); a3 += bf_hi(u3.y);
    }
    if (sl) {
        a0 += bf_lo(us.x); a1 += bf_hi(us.x); a2 += bf_lo(us.y); a3 += bf_hi(us.y);
    }
    // reduce over the 8 slots (lane bits 2..4) within each half-wave
    a0 += __shfl_xor(a0, 4);  a1 += __shfl_xor(a1, 4);  a2 += __shfl_xor(a2, 4);  a3 += __shfl_xor(a3, 4);
    a0 += __shfl_xor(a0, 8);  a1 += __shfl_xor(a1, 8);  a2 += __shfl_xor(a2, 8);  a3 += __shfl_xor(a3, 8);
    a0 += __shfl_xor(a0, 16); a1 += __shfl_xor(a1, 16); a2 += __shfl_xor(a2, 16); a3 += __shfl_xor(a3, 16);
    if ((lane & 31) < 4 && act) {     // lanes 0-3 write A, lanes 32-35 write B
        float dc = dinv[node];
        float4 bb = *(const float4*)(b1 + 4 * j);
        float v0 = fmaxf(dc * a0 + bb.x, 0.f);
        float v1 = fmaxf(dc * a1 + bb.y, 0.f);
        float v2 = fmaxf(dc * a2 + bb.z, 0.f);
        float v3 = fmaxf(dc * a3 + bb.w, 0.f);
        uint2 o;
        o.x = pack_bf(dc * v0, dc * v1);
        o.y = pack_bf(dc * v2, dc * v3);
        f2[(size_t)node * 4 + j] = o;
    }
}

// ---------- fused layer-2 aggregation + W2 matvec + log_softmax: 2 nodes/wave ----------
__global__ void __launch_bounds__(256) agg2out_kernel(const uint2* __restrict__ feat2,
                                                      const float* __restrict__ dinv,
                                                      const int* __restrict__ csr_off,
                                                      const int* __restrict__ csr_src,
                                                      const float* __restrict__ W2,
                                                      const float* __restrict__ b2,
                                                      float* __restrict__ out, int n) {
    __shared__ float W2s[HID * NCLS];
    __shared__ float b2s[NCLS];
    for (int i = threadIdx.x; i < HID * NCLS; i += 256) W2s[i] = W2[i];
    if (threadIdx.x < NCLS) b2s[threadIdx.x] = b2[threadIdx.x];
    __syncthreads();
    int wid = (blockIdx.x * 256 + threadIdx.x) >> 6;
    int w0 = wid << 1;
    if (w0 >= n) return;
    int lane = threadIdx.x & 63;
    int j = lane & 3;
    int s = (lane >> 2) & 7;
    int node = w0 + (lane >> 5);
    bool act = node < n;
    int start = 0, end = 0;
    if (act) { start = csr_off[node]; end = csr_off[node + 1]; }
    bool sl = act && (s == 0);
    uint2 us = feat2[(size_t)(act ? node : 0) * 4 + j];
    float a0 = 0.f, a1 = 0.f, a2 = 0.f, a3 = 0.f;
    for (int base = start + s; base < end; base += 32) {
        int e1 = base + 8, e2 = base + 16, e3 = base + 24;
        bool v1 = e1 < end, v2 = e2 < end, v3 = e3 < end;
        int i0 = csr_src[base];
        int i1 = csr_src[v1 ? e1 : base];
        int i2 = csr_src[v2 ? e2 : base];
        int i3 = csr_src[v3 ? e3 : base];
        uint2 u0 = feat2[(size_t)i0 * 4 + j];
        uint2 u1 = feat2[(size_t)i1 * 4 + j];
        uint2 u2 = feat2[(size_t)i2 * 4 + j];
        uint2 u3 = feat2[(size_t)i3 * 4 + j];
        if (!v1) { u1.x = 0u; u1.y = 0u; }
        if (!v2) { u2.x = 0u; u2.y = 0u; }
        if (!v3) { u3.x = 0u; u3.y = 0u; }
        a0 += bf_lo(u0.x); a1 += bf_hi(u0.x); a2 += bf_lo(u0.y); a3 += bf_hi(u0.y);
        a0 += bf_lo(u1.x); a1 += bf_hi(u1.x); a2 += bf_lo(u1.y); a3 += bf_hi(u1.y);
        a0 += bf_lo(u2.x); a1 += bf_hi(u2.x); a2 += bf_lo(u2.y); a3 += bf_hi(u2.y);
        a0 += bf_lo(u3.x); a1 += bf_hi(u3.x); a2 += bf_lo(u3.y); a3 += bf_hi(u3.y);
    }
    if (sl) {
        a0 += bf_lo(us.x); a1 += bf_hi(us.x); a2 += bf_lo(us.y); a3 += bf_hi(us.y);
    }
    a0 += __shfl_xor(a0, 4);  a1 += __shfl_xor(a1, 4);  a2 += __shfl_xor(a2, 4);  a3 += __shfl_xor(a3, 4);
    a0 += __shfl_xor(a0, 8);  a1 += __shfl_xor(a1, 8);  a2 += __shfl_xor(a2, 8);  a3 += __shfl_xor(a3, 8);
    a0 += __shfl_xor(a0, 16); a1 += __shfl_xor(a1, 16); a2 += __shfl_xor(a2, 16); a3 += __shfl_xor(a3, 16);
    // lane q (0..3) holds A's feats 4q..4q+3; lane 32+q holds B's
    bool hasB = (w0 + 1) < n;
    float dcA = dinv[w0];
    float dcB = hasB ? dinv[w0 + 1] : 0.f;
    float zA = (lane < NCLS) ? b2s[lane] : 0.f;
    float zB = zA;
#pragma unroll
    for (int q = 0; q < 4; ++q) {
        float fA0 = dcA * __shfl(a0, q);
        float fA1 = dcA * __shfl(a1, q);
        float fA2 = dcA * __shfl(a2, q);
        float fA3 = dcA * __shfl(a3, q);
        float fB0 = dcB * __shfl(a0, 32 + q);
        float fB1 = dcB * __shfl(a1, 32 + q);
        float fB2 = dcB * __shfl(a2, 32 + q);
        float fB3 = dcB * __shfl(a3, 32 + q);
        if (lane < NCLS) {
            float w0v = W2s[(4 * q)     * NCLS + lane];
            float w1v = W2s[(4 * q + 1) * NCLS + lane];
            float w2v = W2s[(4 * q + 2) * NCLS + lane];
            float w3v = W2s[(4 * q + 3) * NCLS + lane];
            zA += fA0 * w0v + fA1 * w1v + fA2 * w2v + fA3 * w3v;
            zB += fB0 * w0v + fB1 * w1v + fB2 * w2v + fB3 * w3v;
        }
    }
    // interleaved softmax reductions: A/B chains overlap
    float mA = (lane < NCLS) ? zA : -INFINITY;
    float mB = (lane < NCLS) ? zB : -INFINITY;
#pragma unroll
    for (int off = 1; off < 64; off <<= 1) {
        mA = fmaxf(mA, __shfl_xor(mA, off));
        mB = fmaxf(mB, __shfl_xor(mB, off));
    }
    float eA = (lane < NCLS) ? __expf(zA - mA) : 0.f;
    float eB = (lane < NCLS) ? __expf(zB - mB) : 0.f;
#pragma unroll
    for (int off = 1; off < 64; off <<= 1) {
        eA += __shfl_xor(eA, off);
        eB += __shfl_xor(eB, off);
    }
    float lseA = mA + __logf(eA);
    float lseB = mB + __logf(eB);
    if (lane < NCLS) {
        out[(size_t)w0 * NCLS + lane] = zA - lseA;
        if (hasB) out[(size_t)(w0 + 1) * NCLS + lane] = zB - lseB;
    }
}

extern "C" void kernel_launch(void* const* d_in, const int* in_sizes, int n_in,
                              void* d_out, int out_size, void* d_ws, size_t ws_size,
                              hipStream_t stream) {
    const float* x   = (const float*)d_in[0];
    const int*   ei  = (const int*)d_in[1];   // int32 indices from harness
    const float* W1  = (const float*)d_in[2];
    const float* b1  = (const float*)d_in[3];
    const float* W2  = (const float*)d_in[4];
    const float* b2  = (const float*)d_in[5];
    float*       out = (float*)d_out;

    int n = in_sizes[0] / F_IN;   // 100000 (< 2^17 for packing)
    int E = in_sizes[1] / 2;      // 3200000
    const int* rowp = ei;         // sources
    const int* colp = ei + E;     // targets
    int K = cdiv(n, NB);          // 196 buckets

    char* p = (char*)d_ws;
    auto alloc = [&](size_t bytes) {
        char* q = p;
        p += (bytes + 255) & ~(size_t)255;
        return q;
    };
    int*   bkt_cnt = (int*)  alloc((size_t)K * 4);
    int*   bkt_off = (int*)  alloc(((size_t)K + 1) * 4);
    int*   bkt_cur = (int*)  alloc((size_t)K * 4);
    int*   csr_off = (int*)  alloc(((size_t)n + 1) * 4);
    int*   csr_src = (int*)  alloc((size_t)E * 4);
    float* dinv    = (float*)alloc((size_t)n * 4);
    size_t fbytes = (size_t)n * HID * 2;
    char* region = alloc((size_t)E * 4 > 2 * fbytes ? (size_t)E * 4 : 2 * fbytes);
    int*            entries = (int*)region;
    unsigned short* f1      = (unsigned short*)region;
    uint2*          f2      = (uint2*)(region + fbytes);

    hipMemsetAsync(bkt_cnt, 0, (size_t)K * 4, stream);
    bcount_kernel<<<1024, 256, 0, stream>>>(colp, bkt_cnt, E, K);
    bscan_kernel<<<1, 256, 0, stream>>>(bkt_cnt, bkt_off, bkt_cur, K);
    bscatter_kernel<<<cdiv(E, SPAN), 256, 0, stream>>>(rowp, colp, bkt_cur, entries, E);
    bfill_kernel<<<K, 1024, 0, stream>>>(entries, bkt_off, csr_src, csr_off, dinv, n, E);

    int ntiles = n >> 4;  // 6250 (n divisible by 16)
    xw_kernel<<<cdiv(ntiles, 4), 256, 0, stream>>>(x, W1, dinv, f1, ntiles);
    int npair = cdiv(n, 2);  // 2 nodes per wave
    agg1_kernel<<<cdiv(npair, 4), 256, 0, stream>>>((const uint2*)f1, dinv, csr_off, csr_src, b1, f2, n);
    agg2out_kernel<<<cdiv(npair, 4), 256, 0, stream>>>((const uint2*)f2, dinv, csr_off, csr_src, W2, b2, out, n);
}

// Round 8
// 335.879 us; speedup vs baseline: 1.0368x; 1.0368x over previous
//
#include <hip/hip_runtime.h>

#define F_IN 256
#define HID  16
#define NCLS 40
#define NB   512      // nodes per bucket (dest >> 9)
#define CAP  18944    // max edges per bucket (mean 16.3K + 20 sigma); 74 KB -> 2 blocks/CU
#define SPAN 4096     // edges per bscatter block

static inline int cdiv(int a, int b) { return (a + b - 1) / b; }

typedef short bf16x8 __attribute__((ext_vector_type(8)));
typedef float f32x4  __attribute__((ext_vector_type(4)));

// ---------- bf16 helpers (top 16 bits of fp32, RNE) ----------
__device__ __forceinline__ float bf_lo(unsigned int u) { return __uint_as_float(u << 16); }
__device__ __forceinline__ float bf_hi(unsigned int u) { return __uint_as_float(u & 0xFFFF0000u); }
__device__ __forceinline__ unsigned short f2bf(float a) {
    unsigned int u = __float_as_uint(a);
    return (unsigned short)((u + 0x7FFFu + ((u >> 16) & 1u)) >> 16);
}
__device__ __forceinline__ unsigned int pack_bf(float a, float b) {
    return (unsigned int)f2bf(a) | ((unsigned int)f2bf(b) << 16);
}

// ---------- per-bucket edge counts (LDS hist -> few global atomics) ----------
__global__ void __launch_bounds__(256) bcount_kernel(const int* __restrict__ col,
                                                     int* __restrict__ bkt_cnt, int E, int K) {
    __shared__ int h[256];
    int t = threadIdx.x;
    h[t] = 0;
    __syncthreads();
    int E4 = E >> 2;
    const int4* c4 = (const int4*)col;
    for (int e = blockIdx.x * 256 + t; e < E4; e += gridDim.x * 256) {
        int4 v = c4[e];
        atomicAdd(&h[v.x >> 9], 1);
        atomicAdd(&h[v.y >> 9], 1);
        atomicAdd(&h[v.z >> 9], 1);
        atomicAdd(&h[v.w >> 9], 1);
    }
    for (int e = (E4 << 2) + blockIdx.x * 256 + t; e < E; e += gridDim.x * 256)
        atomicAdd(&h[col[e] >> 9], 1);
    __syncthreads();
    if (t < K && h[t]) atomicAdd(&bkt_cnt[t], h[t]);
}

// ---------- exclusive scan of bucket counts (K <= 256), init cursors ----------
__global__ void __launch_bounds__(256) bscan_kernel(const int* __restrict__ bkt_cnt,
                                                    int* __restrict__ bkt_off,
                                                    int* __restrict__ bkt_cur, int K) {
    __shared__ int s[256];
    int t = threadIdx.x;
    int v = (t < K) ? bkt_cnt[t] : 0;
    s[t] = v;
    __syncthreads();
    for (int off = 1; off < 256; off <<= 1) {
        int x = (t >= off) ? s[t - off] : 0;
        __syncthreads();
        s[t] += x;
        __syncthreads();
    }
    int excl = s[t] - v;
    if (t < K) { bkt_off[t] = excl; bkt_cur[t] = excl; }
    if (t == K - 1) bkt_off[K] = excl + v;
}

// ---------- bucketed scatter: runs of packed entries per (block,bucket) ----------
// entry = row | (local_dest << 17); row < 2^17, local_dest < 512
// Phase-3 loop 8x-unrolled: 8 independent load->LDS-atomic->store chains per
// iteration so their latency windows overlap (SPAN/256 = 16/thread = 2 groups).
__global__ void __launch_bounds__(256) bscatter_kernel(const int* __restrict__ row,
                                                       const int* __restrict__ col,
                                                       int* __restrict__ bkt_cur,
                                                       int* __restrict__ entries, int E) {
    __shared__ int cnt[256];
    __shared__ int base[256];
    int t = threadIdx.x;
    int start = blockIdx.x * SPAN;
    int end = min(start + SPAN, E);
    cnt[t] = 0;
    __syncthreads();
    int m = end - start;
    int m4 = m >> 2;
    const int4* c4 = (const int4*)(col + start);
    for (int i = t; i < m4; i += 256) {
        int4 v = c4[i];
        atomicAdd(&cnt[v.x >> 9], 1);
        atomicAdd(&cnt[v.y >> 9], 1);
        atomicAdd(&cnt[v.z >> 9], 1);
        atomicAdd(&cnt[v.w >> 9], 1);
    }
    for (int i = (m4 << 2) + t; i < m; i += 256)
        atomicAdd(&cnt[col[start + i] >> 9], 1);
    __syncthreads();
    int c = cnt[t];
    base[t] = c ? atomicAdd(&bkt_cur[t], c) : 0;
    cnt[t] = 0;
    __syncthreads();
    int e = start + t;
    for (; e + 1792 < end; e += 2048) {
        int c0 = col[e];
        int c1 = col[e + 256];
        int c2 = col[e + 512];
        int c3 = col[e + 768];
        int c4v = col[e + 1024];
        int c5 = col[e + 1280];
        int c6 = col[e + 1536];
        int c7 = col[e + 1792];
        int r0 = row[e];
        int r1 = row[e + 256];
        int r2 = row[e + 512];
        int r3 = row[e + 768];
        int r4 = row[e + 1024];
        int r5 = row[e + 1280];
        int r6 = row[e + 1536];
        int r7 = row[e + 1792];
        int b0 = c0 >> 9, b1 = c1 >> 9, b2 = c2 >> 9, b3 = c3 >> 9;
        int b4 = c4v >> 9, b5 = c5 >> 9, b6 = c6 >> 9, b7 = c7 >> 9;
        int p0 = base[b0] + atomicAdd(&cnt[b0], 1);
        int p1 = base[b1] + atomicAdd(&cnt[b1], 1);
        int p2 = base[b2] + atomicAdd(&cnt[b2], 1);
        int p3 = base[b3] + atomicAdd(&cnt[b3], 1);
        int p4 = base[b4] + atomicAdd(&cnt[b4], 1);
        int p5 = base[b5] + atomicAdd(&cnt[b5], 1);
        int p6 = base[b6] + atomicAdd(&cnt[b6], 1);
        int p7 = base[b7] + atomicAdd(&cnt[b7], 1);
        entries[p0] = r0 | ((c0 & (NB - 1)) << 17);
        entries[p1] = r1 | ((c1 & (NB - 1)) << 17);
        entries[p2] = r2 | ((c2 & (NB - 1)) << 17);
        entries[p3] = r3 | ((c3 & (NB - 1)) << 17);
        entries[p4] = r4 | ((c4v & (NB - 1)) << 17);
        entries[p5] = r5 | ((c5 & (NB - 1)) << 17);
        entries[p6] = r6 | ((c6 & (NB - 1)) << 17);
        entries[p7] = r7 | ((c7 & (NB - 1)) << 17);
    }
    for (; e < end; e += 256) {
        int cc = col[e];
        int bkt = cc >> 9;
        int pos = base[bkt] + atomicAdd(&cnt[bkt], 1);
        entries[pos] = row[e] | ((cc & (NB - 1)) << 17);
    }
}

// ---------- per-bucket CSR finalize: deg/dinv, shuffle scan, LDS scatter ----------
// (r5 version restored: LDS lsrc staging + coalesced csr_src write; direct
// scattered global stores in r6 regressed ~10us.)
__global__ void __launch_bounds__(512) bfill_kernel(const int* __restrict__ entries,
                                                    const int* __restrict__ bkt_off,
                                                    int* __restrict__ csr_src,
                                                    int* __restrict__ csr_off,
                                                    float* __restrict__ dinv, int n, int E) {
    __shared__ int sdeg[NB];
    __shared__ int soff[NB];
    __shared__ int wtot[8];
    __shared__ int lsrc[CAP];
    int t = threadIdx.x;
    int wv = t >> 6, ln = t & 63;
    int b = blockIdx.x;
    int node0 = b << 9;
    int nn = min(NB, n - node0);
    int seg0 = bkt_off[b], seg1 = bkt_off[b + 1];
    int m = seg1 - seg0;
    sdeg[t] = 0;
    __syncthreads();
    {
        int i = t;
        for (; i + 1536 < m; i += 2048) {
            int u0 = entries[seg0 + i];
            int u1 = entries[seg0 + i + 512];
            int u2 = entries[seg0 + i + 1024];
            int u3 = entries[seg0 + i + 1536];
            atomicAdd(&sdeg[u0 >> 17], 1);
            atomicAdd(&sdeg[u1 >> 17], 1);
            atomicAdd(&sdeg[u2 >> 17], 1);
            atomicAdd(&sdeg[u3 >> 17], 1);
        }
        for (; i < m; i += 512) atomicAdd(&sdeg[entries[seg0 + i] >> 17], 1);
    }
    __syncthreads();
    int v = sdeg[t];
    int inc = v;
#pragma unroll
    for (int o = 1; o < 64; o <<= 1) {
        int u = __shfl_up(inc, o);
        if (ln >= o) inc += u;
    }
    if (ln == 63) wtot[wv] = inc;
    __syncthreads();
    if (wv == 0) {
        int tv = (ln < 8) ? wtot[ln] : 0;
        int ti = tv;
#pragma unroll
        for (int o = 1; o < 8; o <<= 1) {
            int u = __shfl_up(ti, o);
            if (ln >= o) ti += u;
        }
        if (ln < 8) wtot[ln] = ti - tv;  // exclusive wave base
    }
    __syncthreads();
    int excl = inc - v + wtot[wv];
    sdeg[t] = 0;     // reuse as cursor
    soff[t] = excl;
    __syncthreads();
    {
        int i = t;
        for (; i + 1536 < m; i += 2048) {
            int u0 = entries[seg0 + i];
            int u1 = entries[seg0 + i + 512];
            int u2 = entries[seg0 + i + 1024];
            int u3 = entries[seg0 + i + 1536];
            int l0 = u0 >> 17, l1 = u1 >> 17, l2 = u2 >> 17, l3 = u3 >> 17;
            int p0 = soff[l0] + atomicAdd(&sdeg[l0], 1);
            int p1 = soff[l1] + atomicAdd(&sdeg[l1], 1);
            int p2 = soff[l2] + atomicAdd(&sdeg[l2], 1);
            int p3 = soff[l3] + atomicAdd(&sdeg[l3], 1);
            lsrc[p0] = u0 & 0x1FFFF;
            lsrc[p1] = u1 & 0x1FFFF;
            lsrc[p2] = u2 & 0x1FFFF;
            lsrc[p3] = u3 & 0x1FFFF;
        }
        for (; i < m; i += 512) {
            int u = entries[seg0 + i];
            int l = u >> 17;
            int pos = soff[l] + atomicAdd(&sdeg[l], 1);
            lsrc[pos] = u & 0x1FFFF;
        }
    }
    __syncthreads();
    for (int i = t; i < m; i += 512) csr_src[seg0 + i] = lsrc[i];
    if (t < nn) {
        csr_off[node0 + t] = seg0 + excl;
        dinv[node0 + t] = rsqrtf((float)(v + 1));  // +1 self-loop
    }
    if (b == gridDim.x - 1 && t == 0) csr_off[n] = E;
}

// ---------- f1 = bf16( dinv[r] * (x @ W1)[r] ) via MFMA ----------
__global__ void __launch_bounds__(256) xw_kernel(const float* __restrict__ x,
                                                 const float* __restrict__ W1,
                                                 const float* __restrict__ dinv,
                                                 unsigned short* __restrict__ f1,
                                                 int ntiles) {
    int lane = threadIdx.x & 63;
    int m = lane & 15;   // A row / B col / D col
    int q = lane >> 4;   // k-quad
    bf16x8 bfrag[8];
#pragma unroll
    for (int c = 0; c < 8; ++c) {
        const float* wp = W1 + (size_t)(c * 32 + q * 8) * HID + m;
#pragma unroll
        for (int j = 0; j < 8; ++j) bfrag[c][j] = (short)f2bf(wp[(size_t)j * HID]);
    }
    int wid = (blockIdx.x * 256 + threadIdx.x) >> 6;
    if (wid >= ntiles) return;
    int r0 = wid << 4;
    const float* xrow = x + (size_t)(r0 + m) * F_IN + q * 8;
    f32x4 acc = {0.f, 0.f, 0.f, 0.f};
#pragma unroll
    for (int c = 0; c < 8; ++c) {
        float4 v0 = *(const float4*)(xrow + c * 32);
        float4 v1 = *(const float4*)(xrow + c * 32 + 4);
        bf16x8 afrag;
        afrag[0] = (short)f2bf(v0.x);
        afrag[1] = (short)f2bf(v0.y);
        afrag[2] = (short)f2bf(v0.z);
        afrag[3] = (short)f2bf(v0.w);
        afrag[4] = (short)f2bf(v1.x);
        afrag[5] = (short)f2bf(v1.y);
        afrag[6] = (short)f2bf(v1.z);
        afrag[7] = (short)f2bf(v1.w);
        acc = __builtin_amdgcn_mfma_f32_16x16x32_bf16(afrag, bfrag[c], acc, 0, 0, 0);
    }
#pragma unroll
    for (int i = 0; i < 4; ++i) {
        int r = r0 + q * 4 + i;
        f1[(size_t)r * HID + m] = f2bf(dinv[r] * acc[i]);
    }
}

// ---------- layer-1 aggregation: 2 nodes/wave, 8 slots x 4 j (uint2 gathers),
// predicated batches, hoisted self-loop; 1024-thread blocks for full occupancy ----
__global__ void __launch_bounds__(1024) agg1_kernel(const uint2* __restrict__ feat2,
                                                    const float* __restrict__ dinv,
                                                    const int* __restrict__ csr_off,
                                                    const int* __restrict__ csr_src,
                                                    const float* __restrict__ b1,
                                                    uint2* __restrict__ f2, int n) {
    int wid = (blockIdx.x * 1024 + threadIdx.x) >> 6;
    int w0 = wid << 1;
    if (w0 >= n) return;
    int lane = threadIdx.x & 63;
    int j = lane & 3;                 // feature quad: feats 4j..4j+3
    int s = (lane >> 2) & 7;          // slot 0..7
    int node = w0 + (lane >> 5);      // A for lanes<32, B for lanes>=32
    bool act = node < n;
    int start = 0, end = 0;
    if (act) { start = csr_off[node]; end = csr_off[node + 1]; }
    // self-loop load issued unconditionally (clamped addr) so it overlaps the loop
    bool sl = act && (s == 0);
    uint2 us = feat2[(size_t)(act ? node : 0) * 4 + j];
    float a0 = 0.f, a1 = 0.f, a2 = 0.f, a3 = 0.f;
    for (int base = start + s; base < end; base += 32) {
        int e1 = base + 8, e2 = base + 16, e3 = base + 24;
        bool v1 = e1 < end, v2 = e2 < end, v3 = e3 < end;
        int i0 = csr_src[base];
        int i1 = csr_src[v1 ? e1 : base];
        int i2 = csr_src[v2 ? e2 : base];
        int i3 = csr_src[v3 ? e3 : base];
        uint2 u0 = feat2[(size_t)i0 * 4 + j];
        uint2 u1 = feat2[(size_t)i1 * 4 + j];
        uint2 u2 = feat2[(size_t)i2 * 4 + j];
        uint2 u3 = feat2[(size_t)i3 * 4 + j];
        if (!v1) { u1.x = 0u; u1.y = 0u; }
        if (!v2) { u2.x = 0u; u2.y = 0u; }
        if (!v3) { u3.x = 0u; u3.y = 0u; }
        a0 += bf_lo(u0.x); a1 += bf_hi(u0.x); a2 += bf_lo(u0.y); a3 += bf_hi(u0.y);
        a0 += bf_lo(u1.x); a1 += bf_hi(u1.x); a2 += bf_lo(u1.y); a3 += bf_hi(u1.y);
        a0 += bf_lo(u2.x); a1 += bf_hi(u2.x); a2 += bf_lo(u2.y); a3 += bf_hi(u2.y);
        a0 += bf_lo(u3.x); a1 += bf_hi(u3.x); a2 += bf_lo(u3.y); a3 += bf_hi(u3.y);
    }
    if (sl) {
        a0 += bf_lo(us.x); a1 += bf_hi(us.x); a2 += bf_lo(us.y); a3 += bf_hi(us.y);
    }
    // reduce over the 8 slots (lane bits 2..4) within each half-wave
    a0 += __shfl_xor(a0, 4);  a1 += __shfl_xor(a1, 4);  a2 += __shfl_xor(a2, 4);  a3 += __shfl_xor(a3, 4);
    a0 += __shfl_xor(a0, 8);  a1 += __shfl_xor(a1, 8);  a2 += __shfl_xor(a2, 8);  a3 += __shfl_xor(a3, 8);
    a0 += __shfl_xor(a0, 16); a1 += __shfl_xor(a1, 16); a2 += __shfl_xor(a2, 16); a3 += __shfl_xor(a3, 16);
    if ((lane & 31) < 4 && act) {     // lanes 0-3 write A, lanes 32-35 write B
        float dc = dinv[node];
        float4 bb = *(const float4*)(b1 + 4 * j);
        float v0 = fmaxf(dc * a0 + bb.x, 0.f);
        float v1 = fmaxf(dc * a1 + bb.y, 0.f);
        float v2 = fmaxf(dc * a2 + bb.z, 0.f);
        float v3 = fmaxf(dc * a3 + bb.w, 0.f);
        uint2 o;
        o.x = pack_bf(dc * v0, dc * v1);
        o.y = pack_bf(dc * v2, dc * v3);
        f2[(size_t)node * 4 + j] = o;
    }
}

// ---------- fused layer-2 aggregation + W2 matvec + log_softmax: 2 nodes/wave,
// 1024-thread blocks for full occupancy ----------
__global__ void __launch_bounds__(1024) agg2out_kernel(const uint2* __restrict__ feat2,
                                                       const float* __restrict__ dinv,
                                                       const int* __restrict__ csr_off,
                                                       const int* __restrict__ csr_src,
                                                       const float* __restrict__ W2,
                                                       const float* __restrict__ b2,
                                                       float* __restrict__ out, int n) {
    __shared__ float W2s[HID * NCLS];
    __shared__ float b2s[NCLS];
    for (int i = threadIdx.x; i < HID * NCLS; i += 1024) W2s[i] = W2[i];
    if (threadIdx.x < NCLS) b2s[threadIdx.x] = b2[threadIdx.x];
    __syncthreads();
    int wid = (blockIdx.x * 1024 + threadIdx.x) >> 6;
    int w0 = wid << 1;
    if (w0 >= n) return;
    int lane = threadIdx.x & 63;
    int j = lane & 3;
    int s = (lane >> 2) & 7;
    int node = w0 + (lane >> 5);
    bool act = node < n;
    int start = 0, end = 0;
    if (act) { start = csr_off[node]; end = csr_off[node + 1]; }
    bool sl = act && (s == 0);
    uint2 us = feat2[(size_t)(act ? node : 0) * 4 + j];
    float a0 = 0.f, a1 = 0.f, a2 = 0.f, a3 = 0.f;
    for (int base = start + s; base < end; base += 32) {
        int e1 = base + 8, e2 = base + 16, e3 = base + 24;
        bool v1 = e1 < end, v2 = e2 < end, v3 = e3 < end;
        int i0 = csr_src[base];
        int i1 = csr_src[v1 ? e1 : base];
        int i2 = csr_src[v2 ? e2 : base];
        int i3 = csr_src[v3 ? e3 : base];
        uint2 u0 = feat2[(size_t)i0 * 4 + j];
        uint2 u1 = feat2[(size_t)i1 * 4 + j];
        uint2 u2 = feat2[(size_t)i2 * 4 + j];
        uint2 u3 = feat2[(size_t)i3 * 4 + j];
        if (!v1) { u1.x = 0u; u1.y = 0u; }
        if (!v2) { u2.x = 0u; u2.y = 0u; }
        if (!v3) { u3.x = 0u; u3.y = 0u; }
        a0 += bf_lo(u0.x); a1 += bf_hi(u0.x); a2 += bf_lo(u0.y); a3 += bf_hi(u0.y);
        a0 += bf_lo(u1.x); a1 += bf_hi(u1.x); a2 += bf_lo(u1.y); a3 += bf_hi(u1.y);
        a0 += bf_lo(u2.x); a1 += bf_hi(u2.x); a2 += bf_lo(u2.y); a3 += bf_hi(u2.y);
        a0 += bf_lo(u3.x); a1 += bf_hi(u3.x); a2 += bf_lo(u3.y); a3 += bf_hi(u3.y);
    }
    if (sl) {
        a0 += bf_lo(us.x); a1 += bf_hi(us.x); a2 += bf_lo(us.y); a3 += bf_hi(us.y);
    }
    a0 += __shfl_xor(a0, 4);  a1 += __shfl_xor(a1, 4);  a2 += __shfl_xor(a2, 4);  a3 += __shfl_xor(a3, 4);
    a0 += __shfl_xor(a0, 8);  a1 += __shfl_xor(a1, 8);  a2 += __shfl_xor(a2, 8);  a3 += __shfl_xor(a3, 8);
    a0 += __shfl_xor(a0, 16); a1 += __shfl_xor(a1, 16); a2 += __shfl_xor(a2, 16); a3 += __shfl_xor(a3, 16);
    // lane q (0..3) holds A's feats 4q..4q+3; lane 32+q holds B's
    bool hasB = (w0 + 1) < n;
    float dcA = dinv[w0];
    float dcB = hasB ? dinv[w0 + 1] : 0.f;
    float zA = (lane < NCLS) ? b2s[lane] : 0.f;
    float zB = zA;
#pragma unroll
    for (int q = 0; q < 4; ++q) {
        float fA0 = dcA * __shfl(a0, q);
        float fA1 = dcA * __shfl(a1, q);
        float fA2 = dcA * __shfl(a2, q);
        float fA3 = dcA * __shfl(a3, q);
        float fB0 = dcB * __shfl(a0, 32 + q);
        float fB1 = dcB * __shfl(a1, 32 + q);
        float fB2 = dcB * __shfl(a2, 32 + q);
        float fB3 = dcB * __shfl(a3, 32 + q);
        if (lane < NCLS) {
            float w0v = W2s[(4 * q)     * NCLS + lane];
            float w1v = W2s[(4 * q + 1) * NCLS + lane];
            float w2v = W2s[(4 * q + 2) * NCLS + lane];
            float w3v = W2s[(4 * q + 3) * NCLS + lane];
            zA += fA0 * w0v + fA1 * w1v + fA2 * w2v + fA3 * w3v;
            zB += fB0 * w0v + fB1 * w1v + fB2 * w2v + fB3 * w3v;
        }
    }
    // interleaved softmax reductions: A/B chains overlap
    float mA = (lane < NCLS) ? zA : -INFINITY;
    float mB = (lane < NCLS) ? zB : -INFINITY;
#pragma unroll
    for (int off = 1; off < 64; off <<= 1) {
        mA = fmaxf(mA, __shfl_xor(mA, off));
        mB = fmaxf(mB, __shfl_xor(mB, off));
    }
    float eA = (lane < NCLS) ? __expf(zA - mA) : 0.f;
    float eB = (lane < NCLS) ? __expf(zB - mB) : 0.f;
#pragma unroll
    for (int off = 1; off < 64; off <<= 1) {
        eA += __shfl_xor(eA, off);
        eB += __shfl_xor(eB, off);
    }
    float lseA = mA + __logf(eA);
    float lseB = mB + __logf(eB);
    if (lane < NCLS) {
        out[(size_t)w0 * NCLS + lane] = zA - lseA;
        if (hasB) out[(size_t)(w0 + 1) * NCLS + lane] = zB - lseB;
    }
}

extern "C" void kernel_launch(void* const* d_in, const int* in_sizes, int n_in,
                              void* d_out, int out_size, void* d_ws, size_t ws_size,
                              hipStream_t stream) {
    const float* x   = (const float*)d_in[0];
    const int*   ei  = (const int*)d_in[1];   // int32 indices from harness
    const float* W1  = (const float*)d_in[2];
    const float* b1  = (const float*)d_in[3];
    const float* W2  = (const float*)d_in[4];
    const float* b2  = (const float*)d_in[5];
    float*       out = (float*)d_out;

    int n = in_sizes[0] / F_IN;   // 100000 (< 2^17 for packing)
    int E = in_sizes[1] / 2;      // 3200000
    const int* rowp = ei;         // sources
    const int* colp = ei + E;     // targets
    int K = cdiv(n, NB);          // 196 buckets

    char* p = (char*)d_ws;
    auto alloc = [&](size_t bytes) {
        char* q = p;
        p += (bytes + 255) & ~(size_t)255;
        return q;
    };
    int*   bkt_cnt = (int*)  alloc((size_t)K * 4);
    int*   bkt_off = (int*)  alloc(((size_t)K + 1) * 4);
    int*   bkt_cur = (int*)  alloc((size_t)K * 4);
    int*   csr_off = (int*)  alloc(((size_t)n + 1) * 4);
    int*   csr_src = (int*)  alloc((size_t)E * 4);
    float* dinv    = (float*)alloc((size_t)n * 4);
    size_t fbytes = (size_t)n * HID * 2;
    char* region = alloc((size_t)E * 4 > 2 * fbytes ? (size_t)E * 4 : 2 * fbytes);
    int*            entries = (int*)region;
    unsigned short* f1      = (unsigned short*)region;
    uint2*          f2      = (uint2*)(region + fbytes);

    hipMemsetAsync(bkt_cnt, 0, (size_t)K * 4, stream);
    bcount_kernel<<<1024, 256, 0, stream>>>(colp, bkt_cnt, E, K);
    bscan_kernel<<<1, 256, 0, stream>>>(bkt_cnt, bkt_off, bkt_cur, K);
    bscatter_kernel<<<cdiv(E, SPAN), 256, 0, stream>>>(rowp, colp, bkt_cur, entries, E);
    bfill_kernel<<<K, 512, 0, stream>>>(entries, bkt_off, csr_src, csr_off, dinv, n, E);

    int ntiles = n >> 4;  // 6250 (n divisible by 16)
    xw_kernel<<<cdiv(ntiles, 4), 256, 0, stream>>>(x, W1, dinv, f1, ntiles);
    int npair = cdiv(n, 2);  // 2 nodes per wave
    agg1_kernel<<<cdiv(npair, 16), 1024, 0, stream>>>((const uint2*)f1, dinv, csr_off, csr_src, b1, f2, n);
    agg2out_kernel<<<cdiv(npair, 16), 1024, 0, stream>>>((const uint2*)f2, dinv, csr_off, csr_src, W2, b2, out, n);
}